// Round 5
// baseline (338.336 us; speedup 1.0000x reference)
//
#include <hip/hip_runtime.h>

#define DEV __device__ __forceinline__

typedef unsigned short u16;
typedef unsigned short u16x4 __attribute__((ext_vector_type(4)));
typedef unsigned short u16x8 __attribute__((ext_vector_type(8)));
typedef __bf16 bf16x8 __attribute__((ext_vector_type(8)));
typedef float f32x4 __attribute__((ext_vector_type(4)));
typedef float f32x2 __attribute__((ext_vector_type(2)));

#define BATCH 2
#define SEQ   2048
#define DM    1024
#define DI    2048
#define NS    16
#define RK    64
#define MROWS (BATCH * SEQ)   // 4096
#define NPROJ 96              // RK + 2*NS
#define CHUNK 64
#define NCH   (SEQ / CHUNK)   // 32
#define KSLC  8               // proj split-K slices
#define KSZ   (DI / KSLC)     // 256
#define LOG2E 1.44269504f

DEV u16 f2bf(float x) {
  unsigned u = __builtin_bit_cast(unsigned, x);
  u += 0x7fffu + ((u >> 16) & 1u);
  return (u16)(u >> 16);
}
DEV float bf2f(u16 x) {
  unsigned u = ((unsigned)x) << 16;
  return __builtin_bit_cast(float, u);
}

// ---- MFMA dispatch: robust to either builtin signature (v8i16 or v8bf16) ----
template <typename V>
DEV auto mfma_try(V a, V b, f32x4 c, int)
    -> decltype(__builtin_amdgcn_mfma_f32_16x16x32_bf16(a, b, c, 0, 0, 0)) {
  return __builtin_amdgcn_mfma_f32_16x16x32_bf16(a, b, c, 0, 0, 0);
}
template <typename V>
DEV f32x4 mfma_try(V a, V b, f32x4 c, long) {
  return __builtin_amdgcn_mfma_f32_16x16x32_bf16(
      __builtin_bit_cast(bf16x8, a), __builtin_bit_cast(bf16x8, b), c, 0, 0, 0);
}
DEV f32x4 MFMA(u16x8 a, u16x8 b, f32x4 c) { return mfma_try(a, b, c, 0); }

// ---- async global->LDS, 16B per lane (dest = uniform base + lane*16) ----
DEV void gload16(const void* g, void* l) {
  __builtin_amdgcn_global_load_lds(
      (const __attribute__((address_space(1))) unsigned int*)g,
      (__attribute__((address_space(3))) unsigned int*)l, 16, 0, 0);
}

// counted vmcnt wait (literal immediates only)
template <int N>
DEV void waitvm() {
  if constexpr (N == 8)      asm volatile("s_waitcnt vmcnt(8)" ::: "memory");
  else if constexpr (N == 6) asm volatile("s_waitcnt vmcnt(6)" ::: "memory");
  else if constexpr (N == 4) asm volatile("s_waitcnt vmcnt(4)" ::: "memory");
  else if constexpr (N == 3) asm volatile("s_waitcnt vmcnt(3)" ::: "memory");
  else                       asm volatile("s_waitcnt vmcnt(0)" ::: "memory");
}

// Fragment-packed layout for MFMA operands:
//   P[(m>>4)*Kt + (k>>5)][lane][j], lane = ((k&15)>>2)<<4 | (m&15),
//   j = (k&3) | ((k>>4)&1)<<2   (k_local = 4*lq + (j&3) + 16*(j>>2))
// One 16-row x 32-k block = 64 lanes x 16 B = 1024 B, staged linearly.

// ---- pack x (f32 [MROWS][DM]) -> fragment-packed bf16 ----
__global__ __launch_bounds__(256)
void pack_x(const float* __restrict__ in, u16* __restrict__ out) {
  const int tid = blockIdx.x * 256 + threadIdx.x;  // fragment id
  const int lane = tid & 63, gt = tid >> 6;
  const int T = gt & 31, G = gt >> 5;              // Kt = DM/32 = 32
  const int m = (G << 4) + (lane & 15);
  const int k = (T << 5) + ((lane >> 4) << 2);
  const float* p = in + (size_t)m * DM + k;
  f32x4 lo = *(const f32x4*)p;
  f32x4 hi = *(const f32x4*)(p + 16);
  u16x8 o = { f2bf(lo[0]), f2bf(lo[1]), f2bf(lo[2]), f2bf(lo[3]),
              f2bf(hi[0]), f2bf(hi[1]), f2bf(hi[2]), f2bf(hi[3]) };
  *(u16x8*)(out + (size_t)tid * 8) = o;
}

// ---- pack weight W[K][N] (f32) -> fragment-packed bf16 of W^T (n-major) ----
__global__ __launch_bounds__(256)
void pack_w(const float* __restrict__ Wm, u16* __restrict__ out, int K, int N) {
  __shared__ float tile[32][33];
  const int n0 = blockIdx.x * 32, k0 = blockIdx.y * 32;
  const int c = threadIdx.x & 31, r = threadIdx.x >> 5;
#pragma unroll
  for (int rr = 0; rr < 32; rr += 8)
    tile[rr + r][c] = Wm[(size_t)(k0 + rr + r) * N + n0 + c];
  __syncthreads();
  const int t = threadIdx.x;
  if (t < 128) {
    const int nl = t & 31, lq = t >> 5;
    const int n = n0 + nl;
    const int Kt = K >> 5;
    u16x8 o;
#pragma unroll
    for (int j = 0; j < 4; ++j) o[j] = f2bf(tile[4 * lq + j][nl]);
#pragma unroll
    for (int j = 0; j < 4; ++j) o[4 + j] = f2bf(tile[4 * lq + 16 + j][nl]);
    size_t base = ((size_t)((n >> 4) * Kt + (k0 >> 5)) << 9)
                + (((lq << 4) | (n & 15)) << 3);
    *(u16x8*)(out + base) = o;
  }
}

// ---- bf16 MFMA GEMM, fragment-packed, 3-buffer depth-2 pipeline ----
// C[M,N] = A[M,K] @ BT[N,K]^T ; BM x BN tile, BK=32, 4 waves (2x2).
// EPI 0: plain f32 store to O0[M,N]
// EPI 1: col < halfN -> O0[m,col] f32; else O1[m,col-halfN] = bf16(silu(v))
template <int EPI, int BM, int BN>
__global__ __launch_bounds__(256)
void gemm_bt(const u16* __restrict__ A, const u16* __restrict__ BT,
             int M, int N, int K,
             float* __restrict__ O0, u16* __restrict__ O1, int halfN) {
  constexpr int SA = BM / 16, SB = BN / 16;     // 1KB segments per operand
  constexpr int LPW = (SA + SB) / 4;            // gloads per wave per stage
  constexpr int FI = BM / 32, FJ = BN / 32;     // frags per wave
  constexpr int BUFA = BM * 32;                 // u16 per A buffer
  constexpr int BUFB = BN * 32;
  __shared__ u16 As[3 * BUFA];
  __shared__ u16 Bs[3 * BUFB];
  const int t = threadIdx.x;
  const int m0 = blockIdx.y * BM, n0 = blockIdx.x * BN;
  const int lane = t & 63, wid = t >> 6;
  const int wm = (wid >> 1) * (BM / 2), wn = (wid & 1) * (BN / 2);
  const int lr = lane & 15, lq = lane >> 4;
  const int Kt = K >> 5;
  const int ga = m0 >> 4, gb = n0 >> 4;

  f32x4 acc[FI][FJ];
#pragma unroll
  for (int i = 0; i < FI; ++i)
#pragma unroll
    for (int j = 0; j < FJ; ++j) acc[i][j] = f32x4{0.f, 0.f, 0.f, 0.f};

  auto stage = [&](int T, int bi) {
#pragma unroll
    for (int q = 0; q < LPW; ++q) {
      const int s = wid + 4 * q;
      if (s < SA)
        gload16(A + (((size_t)(ga + s) * Kt + T) << 9) + lane * 8,
                (char*)As + (size_t)bi * (BUFA * 2) + s * 1024);
      else
        gload16(BT + (((size_t)(gb + (s - SA)) * Kt + T) << 9) + lane * 8,
                (char*)Bs + (size_t)bi * (BUFB * 2) + (s - SA) * 1024);
    }
  };

  stage(0, 0);
  stage(1, 1);
  int c0 = 0, c1 = 1, c2 = 2;
  for (int T = 0; T < Kt; ++T) {
    if (T + 2 < Kt) { stage(T + 2, c2); waitvm<2 * LPW>(); }
    else if (T + 1 < Kt) { waitvm<LPW>(); }
    else { waitvm<0>(); }
    __builtin_amdgcn_s_barrier();      // stage T visible to all waves
    __builtin_amdgcn_sched_barrier(0);

    u16x8 af[FI], bfr[FJ];
#pragma unroll
    for (int i = 0; i < FI; ++i)
      af[i] = *(const u16x8*)&As[c0 * BUFA + (((wm >> 4) + i) << 9) + lane * 8];
#pragma unroll
    for (int j = 0; j < FJ; ++j)
      bfr[j] = *(const u16x8*)&Bs[c0 * BUFB + (((wn >> 4) + j) << 9) + lane * 8];
#pragma unroll
    for (int i = 0; i < FI; ++i)
#pragma unroll
      for (int j = 0; j < FJ; ++j)
        acc[i][j] = MFMA(af[i], bfr[j], acc[i][j]);

    __builtin_amdgcn_sched_barrier(0);
    __builtin_amdgcn_s_barrier();      // reads done before buf c0 reused (T+3)
    int tmp = c0; c0 = c1; c1 = c2; c2 = tmp;
  }

#pragma unroll
  for (int i = 0; i < FI; ++i) {
    const int row0 = m0 + wm + i * 16 + lq * 4;
#pragma unroll
    for (int j = 0; j < FJ; ++j) {
      const int col = n0 + wn + j * 16 + lr;
#pragma unroll
      for (int r = 0; r < 4; ++r) {
        float v = acc[i][j][r];
        const int row = row0 + r;
        if (EPI == 0) {
          O0[(size_t)row * N + col] = v;
        } else {
          if (col < halfN) {
            O0[(size_t)row * halfN + col] = v;
          } else {
            O1[(size_t)row * halfN + (col - halfN)] =
                f2bf(v / (1.f + __expf(-v)));
          }
        }
      }
    }
  }
}

// ---- depthwise causal conv (k=4) + SiLU ----
__global__ __launch_bounds__(256)
void conv_silu(const float* __restrict__ xin, const float* __restrict__ w,
               const float* __restrict__ cb, float* __restrict__ xc) {
  int idx = blockIdx.x * 256 + threadIdx.x;  // (b, t, d4)
  int d4 = idx & 511;
  int tt = (idx >> 9) & 2047;
  int b = idx >> 20;
  const f32x4* w4 = (const f32x4*)w;
  f32x4 wt[4];
#pragma unroll
  for (int j = 0; j < 4; ++j) wt[j] = w4[d4 * 4 + j];  // taps for d = 4*d4+j
  f32x4 acc = *(const f32x4*)(cb + d4 * 4);
#pragma unroll
  for (int k = 0; k < 4; ++k) {
    int ts = tt - 3 + k;
    if (ts >= 0) {
      f32x4 xv = *(const f32x4*)(xin + ((size_t)(b * 2048 + ts) * 512 + d4) * 4);
      acc[0] += xv[0] * wt[0][k];
      acc[1] += xv[1] * wt[1][k];
      acc[2] += xv[2] * wt[2][k];
      acc[3] += xv[3] * wt[3][k];
    }
  }
  f32x4 o;
#pragma unroll
  for (int j = 0; j < 4; ++j) o[j] = acc[j] / (1.f + __expf(-acc[j]));
  *(f32x4*)(xc + ((size_t)(b * 2048 + tt) * 512 + d4) * 4) = o;
}

// ---- proj split-K stage 1: part[ks][32 rows][96] over K-slice of 256 ----
__global__ __launch_bounds__(256)
void proj_part(const float* __restrict__ xc, const float* __restrict__ Wxp,
               float* __restrict__ part) {
  __shared__ float xs[32][68];
  __shared__ float ws[64][96];
  const int m0 = blockIdx.x * 32;
  const int kbase = blockIdx.y * KSZ;
  const int t = threadIdx.x;
  const int mq = t >> 4, ng = t & 15, nb = ng * 6;
  float acc0[6] = {0.f, 0.f, 0.f, 0.f, 0.f, 0.f};
  float acc1[6] = {0.f, 0.f, 0.f, 0.f, 0.f, 0.f};
  for (int kt = 0; kt < KSZ; kt += 64) {
    __syncthreads();
    {
      int r = t >> 3, c8 = (t & 7) * 8;
      const float* src = xc + (size_t)(m0 + r) * DI + kbase + kt + c8;
      *(f32x4*)&xs[r][c8]     = *(const f32x4*)src;
      *(f32x4*)&xs[r][c8 + 4] = *(const f32x4*)(src + 4);
    }
#pragma unroll
    for (int q = 0; q < 6; ++q) {
      int u = t + q * 256;
      int r = u / 24, c4 = (u % 24) * 4;
      *(f32x4*)&ws[r][c4] = *(const f32x4*)(Wxp + (size_t)(kbase + kt + r) * NPROJ + c4);
    }
    __syncthreads();
#pragma unroll 4
    for (int kk = 0; kk < 64; ++kk) {
      float a0 = xs[mq][kk];
      float a1 = xs[mq + 16][kk];
      f32x2 w01 = *(const f32x2*)&ws[kk][nb];
      f32x2 w23 = *(const f32x2*)&ws[kk][nb + 2];
      f32x2 w45 = *(const f32x2*)&ws[kk][nb + 4];
      acc0[0] += a0 * w01[0]; acc0[1] += a0 * w01[1];
      acc0[2] += a0 * w23[0]; acc0[3] += a0 * w23[1];
      acc0[4] += a0 * w45[0]; acc0[5] += a0 * w45[1];
      acc1[0] += a1 * w01[0]; acc1[1] += a1 * w01[1];
      acc1[2] += a1 * w23[0]; acc1[3] += a1 * w23[1];
      acc1[4] += a1 * w45[0]; acc1[5] += a1 * w45[1];
    }
  }
  const size_t base = ((size_t)blockIdx.y * MROWS + m0) * NPROJ;
#pragma unroll
  for (int j = 0; j < 6; ++j) {
    part[base + (size_t)mq * NPROJ + nb + j]        = acc0[j];
    part[base + (size_t)(mq + 16) * NPROJ + nb + j] = acc1[j];
  }
}

// ---- proj split-K stage 2: fixed-order reduce of KSLC partials ----
__global__ __launch_bounds__(256)
void proj_reduce(const float* __restrict__ part, float* __restrict__ proj) {
  const size_t i = (size_t)(blockIdx.x * 256 + threadIdx.x) * 4;
  f32x4 s = *(const f32x4*)(part + i);
#pragma unroll
  for (int ks = 1; ks < KSLC; ++ks)
    s += *(const f32x4*)(part + (size_t)ks * MROWS * NPROJ + i);
  *(f32x4*)(proj + i) = s;
}

// ---- dt = softplus(proj[:, :64] @ W_dt + b_dt) : K=64 ----
__global__ __launch_bounds__(256)
void dt_kernel(const float* __restrict__ proj, const float* __restrict__ Wdt,
               const float* __restrict__ bdt, float* __restrict__ dtout) {
  __shared__ float ps[16][64];
  const int m0 = blockIdx.y * 16, nb = blockIdx.x * 256;
  const int t = threadIdx.x;
  {
    int r = t >> 4, c4 = (t & 15) * 4;
    *(f32x4*)&ps[r][c4] = *(const f32x4*)(proj + (size_t)(m0 + r) * NPROJ + c4);
  }
  __syncthreads();
  const int n = nb + t;
  float acc[16];
#pragma unroll
  for (int m = 0; m < 16; ++m) acc[m] = 0.f;
  for (int kk = 0; kk < RK; ++kk) {
    float wv = Wdt[(size_t)kk * DI + n];
#pragma unroll
    for (int m = 0; m < 16; ++m) acc[m] += ps[m][kk] * wv;
  }
  float bv = bdt[n];
#pragma unroll
  for (int m = 0; m < 16; ++m) {
    float v = acc[m] + bv;
    v = (v > 20.f) ? v : log1pf(__expf(v));
    dtout[(size_t)(m0 + m) * DI + n] = v;
  }
}

// ---- scan pass 1: thread owns d, 16 states in regs. P via exp2(a2*sum(dt)). ----
__global__ __launch_bounds__(256)
void scan1(const float* __restrict__ dt, const float* __restrict__ xc,
           const float* __restrict__ proj, const float* __restrict__ A_log,
           float* __restrict__ P, float* __restrict__ S) {
  __shared__ float Bs[CHUNK][16];
  const int c = blockIdx.x, dblk = blockIdx.y, b = blockIdx.z;
  const int d = (dblk << 8) + threadIdx.x;
  const size_t mbase = (size_t)b * SEQ + (size_t)c * CHUNK;
  {
    int tt = threadIdx.x >> 2, q = (threadIdx.x & 3) * 4;
    *(f32x4*)&Bs[tt][q] = *(const f32x4*)(proj + (mbase + tt) * NPROJ + RK + q);
  }
  __syncthreads();

  float a2[16], h[16];
#pragma unroll
  for (int i = 0; i < 4; ++i) {
    f32x4 v = *(const f32x4*)(A_log + (size_t)d * NS + i * 4);
    a2[4 * i + 0] = -__expf(v[0]) * LOG2E;
    a2[4 * i + 1] = -__expf(v[1]) * LOG2E;
    a2[4 * i + 2] = -__expf(v[2]) * LOG2E;
    a2[4 * i + 3] = -__expf(v[3]) * LOG2E;
  }
#pragma unroll
  for (int n = 0; n < 16; ++n) h[n] = 0.f;

  float sumdt = 0.f;
  const float* dtp = dt + mbase * DI + d;
  const float* xcp = xc + mbase * DI + d;
  for (int tt = 0; tt < CHUNK; ++tt) {
    float dtv = dtp[(size_t)tt * DI];
    float xv  = xcp[(size_t)tt * DI];
    sumdt += dtv;
    float dx = dtv * xv;
    float Bv[16];
    *(f32x4*)&Bv[0]  = *(const f32x4*)&Bs[tt][0];
    *(f32x4*)&Bv[4]  = *(const f32x4*)&Bs[tt][4];
    *(f32x4*)&Bv[8]  = *(const f32x4*)&Bs[tt][8];
    *(f32x4*)&Bv[12] = *(const f32x4*)&Bs[tt][12];
#pragma unroll
    for (int n = 0; n < 16; ++n)
      h[n] = h[n] * exp2f(dtv * a2[n]) + dx * Bv[n];
  }

  const size_t off = ((size_t)(b * NCH + c) * NS) * DI + d;
#pragma unroll
  for (int n = 0; n < 16; ++n) {
    P[off + (size_t)n * DI] = exp2f(a2[n] * sumdt);
    S[off + (size_t)n * DI] = h[n];
  }
}

// ---- scan pass 2: exclusive scan across chunks ----
__global__ __launch_bounds__(256)
void scan2(const float* __restrict__ P, const float* __restrict__ S,
           float* __restrict__ h0) {
  int idx = blockIdx.x * 256 + threadIdx.x;  // [0, BATCH*NS*DI)
  int b = idx >> 15, rem = idx & 32767;
  float h = 0.f;
#pragma unroll
  for (int c = 0; c < NCH; ++c) {
    size_t off = ((size_t)(b * NCH + c) << 15) + rem;
    h0[off] = h;
    h = P[off] * h + S[off];
  }
}

// ---- scan pass 3: recompute with h0; in-register n-reduction; gate+bf16;
//      writes yg in fragment-packed layout for gemm0 (K=DI, Kt=64) ----
__global__ __launch_bounds__(256)
void scan3(const float* __restrict__ dt, const float* __restrict__ xc,
           const float* __restrict__ proj, const float* __restrict__ A_log,
           const float* __restrict__ Dskip, const float* __restrict__ h0,
           const u16* __restrict__ sz, u16* __restrict__ yg) {
  __shared__ float Bs[CHUNK][16];
  __shared__ float Cs[CHUNK][16];
  const int c = blockIdx.x, dblk = blockIdx.y, b = blockIdx.z;
  const int d = (dblk << 8) + threadIdx.x;
  const size_t mbase = (size_t)b * SEQ + (size_t)c * CHUNK;
  {
    int tt = threadIdx.x >> 2, q = (threadIdx.x & 3) * 4;
    const float* pr = proj + (mbase + tt) * NPROJ + RK;
    *(f32x4*)&Bs[tt][q] = *(const f32x4*)(pr + q);
    *(f32x4*)&Cs[tt][q] = *(const f32x4*)(pr + NS + q);
  }
  __syncthreads();

  float a2[16], h[16];
#pragma unroll
  for (int i = 0; i < 4; ++i) {
    f32x4 v = *(const f32x4*)(A_log + (size_t)d * NS + i * 4);
    a2[4 * i + 0] = -__expf(v[0]) * LOG2E;
    a2[4 * i + 1] = -__expf(v[1]) * LOG2E;
    a2[4 * i + 2] = -__expf(v[2]) * LOG2E;
    a2[4 * i + 3] = -__expf(v[3]) * LOG2E;
  }
  const size_t hoff = ((size_t)(b * NCH + c) * NS) * DI + d;
#pragma unroll
  for (int n = 0; n < 16; ++n) h[n] = h0[hoff + (size_t)n * DI];

  const float dsk = Dskip[d];
  const float* dtp = dt + mbase * DI + d;
  const float* xcp = xc + mbase * DI + d;
  const u16*   szp = sz + mbase * DI + d;

  // packed write base for this d (k-index of gemm0's A)
  const size_t dbase = ((size_t)(d >> 5) << 9) + (((d & 15) >> 2) << 7)
                     + ((d & 3) | (((d >> 4) & 1) << 2));
  const size_t mb4 = ((size_t)(mbase >> 4) << 15);

  for (int tt = 0; tt < CHUNK; ++tt) {
    float dtv = dtp[(size_t)tt * DI];
    float xv  = xcp[(size_t)tt * DI];
    float szv = bf2f(szp[(size_t)tt * DI]);
    float dx = dtv * xv;
    float Bv[16], Cv[16];
    *(f32x4*)&Bv[0]  = *(const f32x4*)&Bs[tt][0];
    *(f32x4*)&Bv[4]  = *(const f32x4*)&Bs[tt][4];
    *(f32x4*)&Bv[8]  = *(const f32x4*)&Bs[tt][8];
    *(f32x4*)&Bv[12] = *(const f32x4*)&Bs[tt][12];
    *(f32x4*)&Cv[0]  = *(const f32x4*)&Cs[tt][0];
    *(f32x4*)&Cv[4]  = *(const f32x4*)&Cs[tt][4];
    *(f32x4*)&Cv[8]  = *(const f32x4*)&Cs[tt][8];
    *(f32x4*)&Cv[12] = *(const f32x4*)&Cs[tt][12];
    float y0 = 0.f, y1 = 0.f, y2 = 0.f, y3 = 0.f;
#pragma unroll
    for (int n = 0; n < 16; ++n) {
      h[n] = h[n] * exp2f(dtv * a2[n]) + dx * Bv[n];
      float yv = h[n] * Cv[n];
      if ((n & 3) == 0) y0 += yv;
      else if ((n & 3) == 1) y1 += yv;
      else if ((n & 3) == 2) y2 += yv;
      else y3 += yv;
    }
    float y = (y0 + y1) + (y2 + y3);
    size_t addr = mb4 + ((size_t)(tt >> 4) << 15) + ((size_t)(tt & 15) << 3) + dbase;
    yg[addr] = f2bf((y + xv * dsk) * szv);
  }
}

extern "C" void kernel_launch(void* const* d_in, const int* in_sizes, int n_in,
                              void* d_out, int out_size, void* d_ws, size_t ws_size,
                              hipStream_t stream) {
  const float* x      = (const float*)d_in[0];
  const float* W_in   = (const float*)d_in[1];
  const float* conv_w = (const float*)d_in[2];
  const float* conv_b = (const float*)d_in[3];
  const float* W_xp   = (const float*)d_in[4];
  const float* W_dt   = (const float*)d_in[5];
  const float* b_dt   = (const float*)d_in[6];
  const float* A_log  = (const float*)d_in[7];
  const float* Dskip  = (const float*)d_in[8];
  const float* W_out  = (const float*)d_in[9];
  float* out = (float*)d_out;

  char* w = (char*)d_ws;
  u16* xbf    = (u16*)w;   w += (size_t)MROWS * DM * 2;            // 8 MB (packed)
  u16* WinT   = (u16*)w;   w += (size_t)(2 * DI) * DM * 2;         // 8 MB (packed)
  u16* WoutT  = (u16*)w;   w += (size_t)DM * DI * 2;               // 4 MB (packed)
  float* xin  = (float*)w; w += (size_t)MROWS * DI * 4;            // 32 MB (aliased: dtb)
  u16* szb    = (u16*)w;   w += (size_t)MROWS * DI * 4;            // slot 32 MB (uses 16, bf16)
  float* xc   = (float*)w; w += (size_t)MROWS * DI * 4;            // 32 MB
  float* proj = (float*)w; w += (size_t)MROWS * NPROJ * 4;         // 1.5 MB
  float* Pb   = (float*)w; w += (size_t)BATCH * NCH * NS * DI * 4; // 8 MB (aliased: yg lo, ppart lo)
  float* Sb   = (float*)w; w += (size_t)BATCH * NCH * NS * DI * 4; // 8 MB (aliased: yg hi, ppart hi)
  float* h0b  = (float*)w; w += (size_t)BATCH * NCH * NS * DI * 4; // 8 MB
  float* dtb  = xin;            // xin dead after conv_silu
  u16*   yg   = (u16*)Pb;       // P/S dead after scan2 (16 MB needed = P+S)
  float* ppart = Pb;            // proj partials (12.6 MB) dead before scan1

  pack_x<<<(MROWS * DM / 8) / 256, 256, 0, stream>>>(x, xbf);
  pack_w<<<dim3((2 * DI) / 32, DM / 32), 256, 0, stream>>>(W_in, WinT, DM, 2 * DI);
  pack_w<<<dim3(DM / 32, DI / 32), 256, 0, stream>>>(W_out, WoutT, DI, DM);

  gemm_bt<1, 128, 128><<<dim3((2 * DI) / 128, MROWS / 128), 256, 0, stream>>>(
      xbf, WinT, MROWS, 2 * DI, DM, xin, szb, DI);

  conv_silu<<<(MROWS * DI / 4) / 256, 256, 0, stream>>>(xin, conv_w, conv_b, xc);

  proj_part<<<dim3(MROWS / 32, KSLC), 256, 0, stream>>>(xc, W_xp, ppart);
  proj_reduce<<<(MROWS * NPROJ / 4) / 256, 256, 0, stream>>>(ppart, proj);

  dt_kernel<<<dim3(DI / 256, MROWS / 16), 256, 0, stream>>>(proj, W_dt, b_dt, dtb);

  scan1<<<dim3(NCH, DI / 256, BATCH), 256, 0, stream>>>(dtb, xc, proj, A_log, Pb, Sb);
  scan2<<<(BATCH * NS * DI) / 256, 256, 0, stream>>>(Pb, Sb, h0b);
  scan3<<<dim3(NCH, DI / 256, BATCH), 256, 0, stream>>>(dtb, xc, proj, A_log, Dskip, h0b, szb, yg);

  gemm_bt<0, 64, 128><<<dim3(DM / 128, MROWS / 64), 256, 0, stream>>>(
      yg, WoutT, MROWS, DM, DI, out, nullptr, 0);
}

// Round 6
// 313.831 us; speedup vs baseline: 1.0781x; 1.0781x over previous
//
#include <hip/hip_runtime.h>

#define DEV __device__ __forceinline__

typedef unsigned short u16;
typedef unsigned short u16x4 __attribute__((ext_vector_type(4)));
typedef unsigned short u16x8 __attribute__((ext_vector_type(8)));
typedef __bf16 bf16x8 __attribute__((ext_vector_type(8)));
typedef float f32x4 __attribute__((ext_vector_type(4)));
typedef float f32x2 __attribute__((ext_vector_type(2)));

#define BATCH 2
#define SEQ   2048
#define DM    1024
#define DI    2048
#define NS    16
#define RK    64
#define MROWS (BATCH * SEQ)   // 4096
#define NPROJ 96              // RK + 2*NS
#define CHUNK 32
#define NCH   (SEQ / CHUNK)   // 64
#define KSLC  8               // proj split-K slices
#define KSZ   (DI / KSLC)     // 256
#define LOG2E 1.44269504f

DEV u16 f2bf(float x) {
  unsigned u = __builtin_bit_cast(unsigned, x);
  u += 0x7fffu + ((u >> 16) & 1u);
  return (u16)(u >> 16);
}
DEV float bf2f(u16 x) {
  unsigned u = ((unsigned)x) << 16;
  return __builtin_bit_cast(float, u);
}

// ---- MFMA dispatch: robust to either builtin signature (v8i16 or v8bf16) ----
template <typename V>
DEV auto mfma_try(V a, V b, f32x4 c, int)
    -> decltype(__builtin_amdgcn_mfma_f32_16x16x32_bf16(a, b, c, 0, 0, 0)) {
  return __builtin_amdgcn_mfma_f32_16x16x32_bf16(a, b, c, 0, 0, 0);
}
template <typename V>
DEV f32x4 mfma_try(V a, V b, f32x4 c, long) {
  return __builtin_amdgcn_mfma_f32_16x16x32_bf16(
      __builtin_bit_cast(bf16x8, a), __builtin_bit_cast(bf16x8, b), c, 0, 0, 0);
}
DEV f32x4 MFMA(u16x8 a, u16x8 b, f32x4 c) { return mfma_try(a, b, c, 0); }

// ---- async global->LDS, 16B per lane (dest = uniform base + lane*16) ----
DEV void gload16(const void* g, void* l) {
  __builtin_amdgcn_global_load_lds(
      (const __attribute__((address_space(1))) unsigned int*)g,
      (__attribute__((address_space(3))) unsigned int*)l, 16, 0, 0);
}

// counted vmcnt wait (literal immediates only)
template <int N>
DEV void waitvm() {
  if constexpr (N == 16)      asm volatile("s_waitcnt vmcnt(16)" ::: "memory");
  else if constexpr (N == 8)  asm volatile("s_waitcnt vmcnt(8)" ::: "memory");
  else if constexpr (N == 6)  asm volatile("s_waitcnt vmcnt(6)" ::: "memory");
  else if constexpr (N == 4)  asm volatile("s_waitcnt vmcnt(4)" ::: "memory");
  else                        asm volatile("s_waitcnt vmcnt(0)" ::: "memory");
}

// Fragment-packed layout for MFMA operands:
//   P[(m>>4)*Kt + (k>>5)][lane][j], lane = ((k&15)>>2)<<4 | (m&15),
//   j = (k&3) | ((k>>4)&1)<<2   (k_local = 4*lq + (j&3) + 16*(j>>2))
// One 16-row x 32-k block = 64 lanes x 16 B = 1024 B, staged linearly.

// ---- pack x (f32 [MROWS][DM]) -> fragment-packed bf16 ----
__global__ __launch_bounds__(256)
void pack_x(const float* __restrict__ in, u16* __restrict__ out) {
  const int tid = blockIdx.x * 256 + threadIdx.x;  // fragment id
  const int lane = tid & 63, gt = tid >> 6;
  const int T = gt & 31, G = gt >> 5;              // Kt = DM/32 = 32
  const int m = (G << 4) + (lane & 15);
  const int k = (T << 5) + ((lane >> 4) << 2);
  const float* p = in + (size_t)m * DM + k;
  f32x4 lo = *(const f32x4*)p;
  f32x4 hi = *(const f32x4*)(p + 16);
  u16x8 o = { f2bf(lo[0]), f2bf(lo[1]), f2bf(lo[2]), f2bf(lo[3]),
              f2bf(hi[0]), f2bf(hi[1]), f2bf(hi[2]), f2bf(hi[3]) };
  *(u16x8*)(out + (size_t)tid * 8) = o;
}

// ---- pack weight W[K][N] (f32) -> fragment-packed bf16 of W^T (n-major) ----
__global__ __launch_bounds__(256)
void pack_w(const float* __restrict__ Wm, u16* __restrict__ out, int K, int N) {
  __shared__ float tile[32][33];
  const int n0 = blockIdx.x * 32, k0 = blockIdx.y * 32;
  const int c = threadIdx.x & 31, r = threadIdx.x >> 5;
#pragma unroll
  for (int rr = 0; rr < 32; rr += 8)
    tile[rr + r][c] = Wm[(size_t)(k0 + rr + r) * N + n0 + c];
  __syncthreads();
  const int t = threadIdx.x;
  if (t < 128) {
    const int nl = t & 31, lq = t >> 5;
    const int n = n0 + nl;
    const int Kt = K >> 5;
    u16x8 o;
#pragma unroll
    for (int j = 0; j < 4; ++j) o[j] = f2bf(tile[4 * lq + j][nl]);
#pragma unroll
    for (int j = 0; j < 4; ++j) o[4 + j] = f2bf(tile[4 * lq + 16 + j][nl]);
    size_t base = ((size_t)((n >> 4) * Kt + (k0 >> 5)) << 9)
                + (((lq << 4) | (n & 15)) << 3);
    *(u16x8*)(out + base) = o;
  }
}

// ---- bf16 MFMA GEMM, fragment-packed, BK=64, double-buffer counted-vmcnt ----
// C[M,N] = A[M,K] @ BT[N,K]^T ; BM x BN tile, 4 waves (2x2).
// Slices along K via blockIdx.z (deterministic split-K): slice z covers
// k-tiles [z*2*ktn, (z+1)*2*ktn), output offset z*M*N.
// EPI 0: plain f32 store to O0[M,N] (per-slice partial)
// EPI 1: col < halfN -> O0[m,col] f32; else O1[m,col-halfN] = bf16(silu(v))
template <int EPI, int BM, int BN>
__global__ __launch_bounds__(256)
void gemm_bt(const u16* __restrict__ A, const u16* __restrict__ BT,
             int KtA, int KtB, int ktn, int M, int N,
             float* __restrict__ O0, u16* __restrict__ O1, int halfN) {
  constexpr int SEGA = (BM / 16) * 2, SEGB = (BN / 16) * 2;  // 1KB segs / step
  constexpr int LPW = (SEGA + SEGB) / 4;                      // gloads per wave
  constexpr int FI = BM / 32, FJ = BN / 32;
  constexpr int BUFA = BM * 64, BUFB = BN * 64;               // u16 per buffer
  __shared__ u16 As[2 * BUFA];
  __shared__ u16 Bs[2 * BUFB];

  // bijective XCD swizzle on the xy-plane (nwg % 8 == 0 for all launches)
  const int nwg = gridDim.x * gridDim.y;
  int wg = blockIdx.y * gridDim.x + blockIdx.x;
  wg = (wg & 7) * (nwg >> 3) + (wg >> 3);
  const int bx = wg % gridDim.x, by = wg / gridDim.x;
  const int kt0 = blockIdx.z * ktn * 2;
  float* __restrict__ O0z = O0 + (size_t)blockIdx.z * M * N;

  const int t = threadIdx.x;
  const int m0 = by * BM, n0 = bx * BN;
  const int lane = t & 63, wid = t >> 6;
  const int wm = (wid >> 1) * (BM / 2), wn = (wid & 1) * (BN / 2);
  const int lr = lane & 15, lq = lane >> 4;
  const int ga = m0 >> 4, gb = n0 >> 4;

  f32x4 acc[FI][FJ];
#pragma unroll
  for (int i = 0; i < FI; ++i)
#pragma unroll
    for (int j = 0; j < FJ; ++j) acc[i][j] = f32x4{0.f, 0.f, 0.f, 0.f};

  auto stage = [&](int T, int bi) {
#pragma unroll
    for (int q = 0; q < LPW; ++q) {
      const int s = wid * LPW + q;
      if (s < SEGA) {
        const int g = s >> 1, sk = s & 1;
        gload16(A + (((size_t)(ga + g) * KtA + kt0 + 2 * T + sk) << 9) + lane * 8,
                (char*)As + (size_t)bi * (BUFA * 2) + s * 1024);
      } else {
        const int s2 = s - SEGA, g = s2 >> 1, sk = s2 & 1;
        gload16(BT + (((size_t)(gb + g) * KtB + kt0 + 2 * T + sk) << 9) + lane * 8,
                (char*)Bs + (size_t)bi * (BUFB * 2) + s2 * 1024);
      }
    }
  };

  stage(0, 0);
  int cur = 0;
  for (int T = 0; T < ktn; ++T) {
    if (T + 1 < ktn) { stage(T + 1, cur ^ 1); waitvm<LPW>(); }
    else             { waitvm<0>(); }
    __builtin_amdgcn_s_barrier();       // stage T visible to all waves
    __builtin_amdgcn_sched_barrier(0);

#pragma unroll
    for (int sk = 0; sk < 2; ++sk) {
      u16x8 af[FI], bfr[FJ];
#pragma unroll
      for (int i = 0; i < FI; ++i)
        af[i] = *(const u16x8*)
            &As[cur * BUFA + (((((wm >> 4) + i) << 1) + sk) << 9) + lane * 8];
#pragma unroll
      for (int j = 0; j < FJ; ++j)
        bfr[j] = *(const u16x8*)
            &Bs[cur * BUFB + (((((wn >> 4) + j) << 1) + sk) << 9) + lane * 8];
#pragma unroll
      for (int i = 0; i < FI; ++i)
#pragma unroll
        for (int j = 0; j < FJ; ++j)
          acc[i][j] = MFMA(af[i], bfr[j], acc[i][j]);
    }

    __builtin_amdgcn_sched_barrier(0);
    __builtin_amdgcn_s_barrier();       // reads done before buffer reuse
    cur ^= 1;
  }

#pragma unroll
  for (int i = 0; i < FI; ++i) {
    const int row0 = m0 + wm + i * 16 + lq * 4;
#pragma unroll
    for (int j = 0; j < FJ; ++j) {
      const int col = n0 + wn + j * 16 + lr;
#pragma unroll
      for (int r = 0; r < 4; ++r) {
        float v = acc[i][j][r];
        const int row = row0 + r;
        if (EPI == 0) {
          O0z[(size_t)row * N + col] = v;
        } else {
          if (col < halfN) {
            O0z[(size_t)row * halfN + col] = v;
          } else {
            O1[(size_t)row * halfN + (col - halfN)] =
                f2bf(v / (1.f + __expf(-v)));
          }
        }
      }
    }
  }
}

// ---- fixed-order split-K reduce: out = p0 + p1 ----
__global__ __launch_bounds__(256)
void add2(const float* __restrict__ p, float* __restrict__ out) {
  const size_t i = (size_t)(blockIdx.x * 256 + threadIdx.x) * 4;
  f32x4 a = *(const f32x4*)(p + i);
  f32x4 b = *(const f32x4*)(p + (size_t)MROWS * DM + i);
  *(f32x4*)(out + i) = a + b;
}

// ---- depthwise causal conv (k=4) + SiLU ----
__global__ __launch_bounds__(256)
void conv_silu(const float* __restrict__ xin, const float* __restrict__ w,
               const float* __restrict__ cb, float* __restrict__ xc) {
  int idx = blockIdx.x * 256 + threadIdx.x;  // (b, t, d4)
  int d4 = idx & 511;
  int tt = (idx >> 9) & 2047;
  int b = idx >> 20;
  const f32x4* w4 = (const f32x4*)w;
  f32x4 wt[4];
#pragma unroll
  for (int j = 0; j < 4; ++j) wt[j] = w4[d4 * 4 + j];  // taps for d = 4*d4+j
  f32x4 acc = *(const f32x4*)(cb + d4 * 4);
#pragma unroll
  for (int k = 0; k < 4; ++k) {
    int ts = tt - 3 + k;
    if (ts >= 0) {
      f32x4 xv = *(const f32x4*)(xin + ((size_t)(b * 2048 + ts) * 512 + d4) * 4);
      acc[0] += xv[0] * wt[0][k];
      acc[1] += xv[1] * wt[1][k];
      acc[2] += xv[2] * wt[2][k];
      acc[3] += xv[3] * wt[3][k];
    }
  }
  f32x4 o;
#pragma unroll
  for (int j = 0; j < 4; ++j) o[j] = acc[j] / (1.f + __expf(-acc[j]));
  *(f32x4*)(xc + ((size_t)(b * 2048 + tt) * 512 + d4) * 4) = o;
}

// ---- proj split-K stage 1: part[ks][32 rows][96] over K-slice of 256 ----
__global__ __launch_bounds__(256)
void proj_part(const float* __restrict__ xc, const float* __restrict__ Wxp,
               float* __restrict__ part) {
  __shared__ float xs[32][68];
  __shared__ float ws[64][96];
  const int m0 = blockIdx.x * 32;
  const int kbase = blockIdx.y * KSZ;
  const int t = threadIdx.x;
  const int mq = t >> 4, ng = t & 15, nb = ng * 6;
  float acc0[6] = {0.f, 0.f, 0.f, 0.f, 0.f, 0.f};
  float acc1[6] = {0.f, 0.f, 0.f, 0.f, 0.f, 0.f};
  for (int kt = 0; kt < KSZ; kt += 64) {
    __syncthreads();
    {
      int r = t >> 3, c8 = (t & 7) * 8;
      const float* src = xc + (size_t)(m0 + r) * DI + kbase + kt + c8;
      *(f32x4*)&xs[r][c8]     = *(const f32x4*)src;
      *(f32x4*)&xs[r][c8 + 4] = *(const f32x4*)(src + 4);
    }
#pragma unroll
    for (int q = 0; q < 6; ++q) {
      int u = t + q * 256;
      int r = u / 24, c4 = (u % 24) * 4;
      *(f32x4*)&ws[r][c4] = *(const f32x4*)(Wxp + (size_t)(kbase + kt + r) * NPROJ + c4);
    }
    __syncthreads();
#pragma unroll 4
    for (int kk = 0; kk < 64; ++kk) {
      float a0 = xs[mq][kk];
      float a1 = xs[mq + 16][kk];
      f32x2 w01 = *(const f32x2*)&ws[kk][nb];
      f32x2 w23 = *(const f32x2*)&ws[kk][nb + 2];
      f32x2 w45 = *(const f32x2*)&ws[kk][nb + 4];
      acc0[0] += a0 * w01[0]; acc0[1] += a0 * w01[1];
      acc0[2] += a0 * w23[0]; acc0[3] += a0 * w23[1];
      acc0[4] += a0 * w45[0]; acc0[5] += a0 * w45[1];
      acc1[0] += a1 * w01[0]; acc1[1] += a1 * w01[1];
      acc1[2] += a1 * w23[0]; acc1[3] += a1 * w23[1];
      acc1[4] += a1 * w45[0]; acc1[5] += a1 * w45[1];
    }
  }
  const size_t base = ((size_t)blockIdx.y * MROWS + m0) * NPROJ;
#pragma unroll
  for (int j = 0; j < 6; ++j) {
    part[base + (size_t)mq * NPROJ + nb + j]        = acc0[j];
    part[base + (size_t)(mq + 16) * NPROJ + nb + j] = acc1[j];
  }
}

// ---- proj split-K stage 2: fixed-order reduce of KSLC partials ----
__global__ __launch_bounds__(256)
void proj_reduce(const float* __restrict__ part, float* __restrict__ proj) {
  const size_t i = (size_t)(blockIdx.x * 256 + threadIdx.x) * 4;
  f32x4 s = *(const f32x4*)(part + i);
#pragma unroll
  for (int ks = 1; ks < KSLC; ++ks)
    s += *(const f32x4*)(part + (size_t)ks * MROWS * NPROJ + i);
  *(f32x4*)(proj + i) = s;
}

// ---- dt = softplus(proj[:, :64] @ W_dt + b_dt) : K=64 ----
__global__ __launch_bounds__(256)
void dt_kernel(const float* __restrict__ proj, const float* __restrict__ Wdt,
               const float* __restrict__ bdt, float* __restrict__ dtout) {
  __shared__ float ps[16][64];
  const int m0 = blockIdx.y * 16, nb = blockIdx.x * 256;
  const int t = threadIdx.x;
  {
    int r = t >> 4, c4 = (t & 15) * 4;
    *(f32x4*)&ps[r][c4] = *(const f32x4*)(proj + (size_t)(m0 + r) * NPROJ + c4);
  }
  __syncthreads();
  const int n = nb + t;
  float acc[16];
#pragma unroll
  for (int m = 0; m < 16; ++m) acc[m] = 0.f;
  for (int kk = 0; kk < RK; ++kk) {
    float wv = Wdt[(size_t)kk * DI + n];
#pragma unroll
    for (int m = 0; m < 16; ++m) acc[m] += ps[m][kk] * wv;
  }
  float bv = bdt[n];
#pragma unroll
  for (int m = 0; m < 16; ++m) {
    float v = acc[m] + bv;
    v = (v > 20.f) ? v : log1pf(__expf(v));
    dtout[(size_t)(m0 + m) * DI + n] = v;
  }
}

// ---- scan pass 1: thread owns d, 16 states in regs. P via exp2(a2*sum(dt)). ----
__global__ __launch_bounds__(256)
void scan1(const float* __restrict__ dt, const float* __restrict__ xc,
           const float* __restrict__ proj, const float* __restrict__ A_log,
           float* __restrict__ P, float* __restrict__ S) {
  __shared__ float Bs[CHUNK][16];
  const int c = blockIdx.x, dblk = blockIdx.y, b = blockIdx.z;
  const int d = (dblk << 8) + threadIdx.x;
  const size_t mbase = (size_t)b * SEQ + (size_t)c * CHUNK;
  if (threadIdx.x < CHUNK * 4) {
    int tt = threadIdx.x >> 2, q = (threadIdx.x & 3) * 4;
    *(f32x4*)&Bs[tt][q] = *(const f32x4*)(proj + (mbase + tt) * NPROJ + RK + q);
  }
  __syncthreads();

  float a2[16], h[16];
#pragma unroll
  for (int i = 0; i < 4; ++i) {
    f32x4 v = *(const f32x4*)(A_log + (size_t)d * NS + i * 4);
    a2[4 * i + 0] = -__expf(v[0]) * LOG2E;
    a2[4 * i + 1] = -__expf(v[1]) * LOG2E;
    a2[4 * i + 2] = -__expf(v[2]) * LOG2E;
    a2[4 * i + 3] = -__expf(v[3]) * LOG2E;
  }
#pragma unroll
  for (int n = 0; n < 16; ++n) h[n] = 0.f;

  float sumdt = 0.f;
  const float* dtp = dt + mbase * DI + d;
  const float* xcp = xc + mbase * DI + d;
  for (int tt = 0; tt < CHUNK; ++tt) {
    float dtv = dtp[(size_t)tt * DI];
    float xv  = xcp[(size_t)tt * DI];
    sumdt += dtv;
    float dx = dtv * xv;
    float Bv[16];
    *(f32x4*)&Bv[0]  = *(const f32x4*)&Bs[tt][0];
    *(f32x4*)&Bv[4]  = *(const f32x4*)&Bs[tt][4];
    *(f32x4*)&Bv[8]  = *(const f32x4*)&Bs[tt][8];
    *(f32x4*)&Bv[12] = *(const f32x4*)&Bs[tt][12];
#pragma unroll
    for (int n = 0; n < 16; ++n)
      h[n] = h[n] * exp2f(dtv * a2[n]) + dx * Bv[n];
  }

  const size_t off = ((size_t)(b * NCH + c) * NS) * DI + d;
#pragma unroll
  for (int n = 0; n < 16; ++n) {
    P[off + (size_t)n * DI] = exp2f(a2[n] * sumdt);
    S[off + (size_t)n * DI] = h[n];
  }
}

// ---- scan pass 2: exclusive scan across chunks ----
__global__ __launch_bounds__(256)
void scan2(const float* __restrict__ P, const float* __restrict__ S,
           float* __restrict__ h0) {
  int idx = blockIdx.x * 256 + threadIdx.x;  // [0, BATCH*NS*DI)
  int b = idx >> 15, rem = idx & 32767;
  float h = 0.f;
#pragma unroll 8
  for (int c = 0; c < NCH; ++c) {
    size_t off = ((size_t)(b * NCH + c) << 15) + rem;
    h0[off] = h;
    h = P[off] * h + S[off];
  }
}

// ---- scan pass 3: recompute with h0; in-register n-reduction; gate+bf16;
//      writes yg in fragment-packed layout for gemm0 (K=DI, Kt=64) ----
__global__ __launch_bounds__(256)
void scan3(const float* __restrict__ dt, const float* __restrict__ xc,
           const float* __restrict__ proj, const float* __restrict__ A_log,
           const float* __restrict__ Dskip, const float* __restrict__ h0,
           const u16* __restrict__ sz, u16* __restrict__ yg) {
  __shared__ float Bs[CHUNK][16];
  __shared__ float Cs[CHUNK][16];
  const int c = blockIdx.x, dblk = blockIdx.y, b = blockIdx.z;
  const int d = (dblk << 8) + threadIdx.x;
  const size_t mbase = (size_t)b * SEQ + (size_t)c * CHUNK;
  if (threadIdx.x < CHUNK * 4) {
    int tt = threadIdx.x >> 2, q = (threadIdx.x & 3) * 4;
    *(f32x4*)&Bs[tt][q] = *(const f32x4*)(proj + (mbase + tt) * NPROJ + RK + q);
  } else if (threadIdx.x < CHUNK * 8) {
    int u = threadIdx.x - CHUNK * 4;
    int tt = u >> 2, q = (u & 3) * 4;
    *(f32x4*)&Cs[tt][q] = *(const f32x4*)(proj + (mbase + tt) * NPROJ + RK + NS + q);
  }
  __syncthreads();

  float a2[16], h[16];
#pragma unroll
  for (int i = 0; i < 4; ++i) {
    f32x4 v = *(const f32x4*)(A_log + (size_t)d * NS + i * 4);
    a2[4 * i + 0] = -__expf(v[0]) * LOG2E;
    a2[4 * i + 1] = -__expf(v[1]) * LOG2E;
    a2[4 * i + 2] = -__expf(v[2]) * LOG2E;
    a2[4 * i + 3] = -__expf(v[3]) * LOG2E;
  }
  const size_t hoff = ((size_t)(b * NCH + c) * NS) * DI + d;
#pragma unroll
  for (int n = 0; n < 16; ++n) h[n] = h0[hoff + (size_t)n * DI];

  const float dsk = Dskip[d];
  const float* dtp = dt + mbase * DI + d;
  const float* xcp = xc + mbase * DI + d;
  const u16*   szp = sz + mbase * DI + d;

  // packed write base for this d (k-index of gemm0's A)
  const size_t dbase = ((size_t)(d >> 5) << 9) + (((d & 15) >> 2) << 7)
                     + ((d & 3) | (((d >> 4) & 1) << 2));
  const size_t mb4 = ((size_t)(mbase >> 4) << 15);

  for (int tt = 0; tt < CHUNK; ++tt) {
    float dtv = dtp[(size_t)tt * DI];
    float xv  = xcp[(size_t)tt * DI];
    float szv = bf2f(szp[(size_t)tt * DI]);
    float dx = dtv * xv;
    float Bv[16], Cv[16];
    *(f32x4*)&Bv[0]  = *(const f32x4*)&Bs[tt][0];
    *(f32x4*)&Bv[4]  = *(const f32x4*)&Bs[tt][4];
    *(f32x4*)&Bv[8]  = *(const f32x4*)&Bs[tt][8];
    *(f32x4*)&Bv[12] = *(const f32x4*)&Bs[tt][12];
    *(f32x4*)&Cv[0]  = *(const f32x4*)&Cs[tt][0];
    *(f32x4*)&Cv[4]  = *(const f32x4*)&Cs[tt][4];
    *(f32x4*)&Cv[8]  = *(const f32x4*)&Cs[tt][8];
    *(f32x4*)&Cv[12] = *(const f32x4*)&Cs[tt][12];
    float y0 = 0.f, y1 = 0.f, y2 = 0.f, y3 = 0.f;
#pragma unroll
    for (int n = 0; n < 16; ++n) {
      h[n] = h[n] * exp2f(dtv * a2[n]) + dx * Bv[n];
      float yv = h[n] * Cv[n];
      if ((n & 3) == 0) y0 += yv;
      else if ((n & 3) == 1) y1 += yv;
      else if ((n & 3) == 2) y2 += yv;
      else y3 += yv;
    }
    float y = (y0 + y1) + (y2 + y3);
    size_t addr = mb4 + ((size_t)(tt >> 4) << 15) + ((size_t)(tt & 15) << 3) + dbase;
    yg[addr] = f2bf((y + xv * dsk) * szv);
  }
}

extern "C" void kernel_launch(void* const* d_in, const int* in_sizes, int n_in,
                              void* d_out, int out_size, void* d_ws, size_t ws_size,
                              hipStream_t stream) {
  const float* x      = (const float*)d_in[0];
  const float* W_in   = (const float*)d_in[1];
  const float* conv_w = (const float*)d_in[2];
  const float* conv_b = (const float*)d_in[3];
  const float* W_xp   = (const float*)d_in[4];
  const float* W_dt   = (const float*)d_in[5];
  const float* b_dt   = (const float*)d_in[6];
  const float* A_log  = (const float*)d_in[7];
  const float* Dskip  = (const float*)d_in[8];
  const float* W_out  = (const float*)d_in[9];
  float* out = (float*)d_out;

  char* w = (char*)d_ws;
  u16* xbf    = (u16*)w;   w += (size_t)MROWS * DM * 2;            // 8 MB (packed)
  u16* WinT   = (u16*)w;   w += (size_t)(2 * DI) * DM * 2;         // 8 MB (packed)
  u16* WoutT  = (u16*)w;   w += (size_t)DM * DI * 2;               // 4 MB (packed)
  float* xin  = (float*)w; w += (size_t)MROWS * DI * 4;            // 32 MB (alias: dtb)
  u16* szb    = (u16*)w;   w += (size_t)MROWS * DI * 2;            // 16 MB (bf16)
  float* xc   = (float*)w; w += (size_t)MROWS * DI * 4;            // 32 MB (alias: gemm0 partials)
  float* proj = (float*)w; w += (size_t)MROWS * NPROJ * 4;         // 1.5 MB
  float* Pb   = (float*)w; w += (size_t)BATCH * NCH * NS * DI * 4; // 16 MB (alias: yg, ppart)
  float* Sb   = (float*)w; w += (size_t)BATCH * NCH * NS * DI * 4; // 16 MB
  float* h0b  = (float*)w; w += (size_t)BATCH * NCH * NS * DI * 4; // 16 MB
  float* dtb  = xin;            // xin dead after conv_silu
  u16*   yg   = (u16*)Pb;       // P dead after scan2 (16 MB)
  float* ppart = Pb;            // proj partials (12.6 MB) dead before scan1
  float* pK   = xc;             // gemm0 split-K partials (2 x 16 MB); xc dead after scan3

  pack_x<<<(MROWS * DM / 8) / 256, 256, 0, stream>>>(x, xbf);
  pack_w<<<dim3((2 * DI) / 32, DM / 32), 256, 0, stream>>>(W_in, WinT, DM, 2 * DI);
  pack_w<<<dim3(DM / 32, DI / 32), 256, 0, stream>>>(W_out, WoutT, DI, DM);

  // gemm1: M=4096, N=4096, K=1024 (Kt=32, ktn=16 BK64-steps), no split
  gemm_bt<1, 128, 128><<<dim3((2 * DI) / 128, MROWS / 128, 1), 256, 0, stream>>>(
      xbf, WinT, DM / 32, DM / 32, DM / 64, MROWS, 2 * DI, xin, szb, DI);

  conv_silu<<<(MROWS * DI / 4) / 256, 256, 0, stream>>>(xin, conv_w, conv_b, xc);

  proj_part<<<dim3(MROWS / 32, KSLC), 256, 0, stream>>>(xc, W_xp, ppart);
  proj_reduce<<<(MROWS * NPROJ / 4) / 256, 256, 0, stream>>>(ppart, proj);

  dt_kernel<<<dim3(DI / 256, MROWS / 16), 256, 0, stream>>>(proj, W_dt, b_dt, dtb);

  scan1<<<dim3(NCH, DI / 256, BATCH), 256, 0, stream>>>(dtb, xc, proj, A_log, Pb, Sb);
  scan2<<<(BATCH * NS * DI) / 256, 256, 0, stream>>>(Pb, Sb, h0b);
  scan3<<<dim3(NCH, DI / 256, BATCH), 256, 0, stream>>>(dtb, xc, proj, A_log, Dskip, h0b, szb, yg);

  // gemm0: M=4096, N=1024, K=2048; split-K=2 via blockIdx.z (ktn=16 each)
  gemm_bt<0, 128, 128><<<dim3(DM / 128, MROWS / 128, 2), 256, 0, stream>>>(
      yg, WoutT, DI / 32, DI / 32, DI / 128, MROWS, DM, pK, nullptr, 0);
  add2<<<(MROWS * DM / 4) / 256, 256, 0, stream>>>(pK, out);
}

// Round 7
// 302.885 us; speedup vs baseline: 1.1170x; 1.0361x over previous
//
#include <hip/hip_runtime.h>

#define DEV __device__ __forceinline__

typedef unsigned short u16;
typedef unsigned short u16x4 __attribute__((ext_vector_type(4)));
typedef unsigned short u16x8 __attribute__((ext_vector_type(8)));
typedef __bf16 bf16x8 __attribute__((ext_vector_type(8)));
typedef float f32x4 __attribute__((ext_vector_type(4)));
typedef float f32x2 __attribute__((ext_vector_type(2)));

#define BATCH 2
#define SEQ   2048
#define DM    1024
#define DI    2048
#define NS    16
#define RK    64
#define MROWS (BATCH * SEQ)   // 4096
#define NPROJ 96              // RK + 2*NS
#define CHUNK 32
#define NCH   (SEQ / CHUNK)   // 64
#define KSLC  8               // proj split-K slices
#define LOG2E 1.44269504f

DEV u16 f2bf(float x) {
  unsigned u = __builtin_bit_cast(unsigned, x);
  u += 0x7fffu + ((u >> 16) & 1u);
  return (u16)(u >> 16);
}
DEV float bf2f(u16 x) {
  unsigned u = ((unsigned)x) << 16;
  return __builtin_bit_cast(float, u);
}

// ---- MFMA dispatch: robust to either builtin signature (v8i16 or v8bf16) ----
template <typename V>
DEV auto mfma_try(V a, V b, f32x4 c, int)
    -> decltype(__builtin_amdgcn_mfma_f32_16x16x32_bf16(a, b, c, 0, 0, 0)) {
  return __builtin_amdgcn_mfma_f32_16x16x32_bf16(a, b, c, 0, 0, 0);
}
template <typename V>
DEV f32x4 mfma_try(V a, V b, f32x4 c, long) {
  return __builtin_amdgcn_mfma_f32_16x16x32_bf16(
      __builtin_bit_cast(bf16x8, a), __builtin_bit_cast(bf16x8, b), c, 0, 0, 0);
}
DEV f32x4 MFMA(u16x8 a, u16x8 b, f32x4 c) { return mfma_try(a, b, c, 0); }

// ---- async global->LDS, 16B per lane (dest = uniform base + lane*16) ----
DEV void gload16(const void* g, void* l) {
  __builtin_amdgcn_global_load_lds(
      (const __attribute__((address_space(1))) unsigned int*)g,
      (__attribute__((address_space(3))) unsigned int*)l, 16, 0, 0);
}

// counted vmcnt wait (literal immediates only)
template <int N>
DEV void waitvm() {
  if constexpr (N == 16)      asm volatile("s_waitcnt vmcnt(16)" ::: "memory");
  else if constexpr (N == 8)  asm volatile("s_waitcnt vmcnt(8)" ::: "memory");
  else if constexpr (N == 7)  asm volatile("s_waitcnt vmcnt(7)" ::: "memory");
  else if constexpr (N == 6)  asm volatile("s_waitcnt vmcnt(6)" ::: "memory");
  else if constexpr (N == 5)  asm volatile("s_waitcnt vmcnt(5)" ::: "memory");
  else if constexpr (N == 4)  asm volatile("s_waitcnt vmcnt(4)" ::: "memory");
  else                        asm volatile("s_waitcnt vmcnt(0)" ::: "memory");
}

// Fragment-packed layout for MFMA operands:
//   P[(m>>4)*Kt + (k>>5)][lane][j], lane = ((k&15)>>2)<<4 | (m&15),
//   j = (k&3) | ((k>>4)&1)<<2   (k_local = 4*lq + (j&3) + 16*(j>>2))
// One 16-row x 32-k block = 64 lanes x 16 B = 1024 B, staged linearly.

// ---- pack x (f32 [MROWS][DM]) -> fragment-packed bf16 ----
__global__ __launch_bounds__(256)
void pack_x(const float* __restrict__ in, u16* __restrict__ out) {
  const int tid = blockIdx.x * 256 + threadIdx.x;  // fragment id
  const int lane = tid & 63, gt = tid >> 6;
  const int T = gt & 31, G = gt >> 5;              // Kt = DM/32 = 32
  const int m = (G << 4) + (lane & 15);
  const int k = (T << 5) + ((lane >> 4) << 2);
  const float* p = in + (size_t)m * DM + k;
  f32x4 lo = *(const f32x4*)p;
  f32x4 hi = *(const f32x4*)(p + 16);
  u16x8 o = { f2bf(lo[0]), f2bf(lo[1]), f2bf(lo[2]), f2bf(lo[3]),
              f2bf(hi[0]), f2bf(hi[1]), f2bf(hi[2]), f2bf(hi[3]) };
  *(u16x8*)(out + (size_t)tid * 8) = o;
}

// ---- pack weight W[K][N] (f32) -> fragment-packed bf16 of W^T (n-major) ----
__global__ __launch_bounds__(256)
void pack_w(const float* __restrict__ Wm, u16* __restrict__ out, int K, int N) {
  __shared__ float tile[32][33];
  const int n0 = blockIdx.x * 32, k0 = blockIdx.y * 32;
  const int c = threadIdx.x & 31, r = threadIdx.x >> 5;
#pragma unroll
  for (int rr = 0; rr < 32; rr += 8)
    tile[rr + r][c] = Wm[(size_t)(k0 + rr + r) * N + n0 + c];
  __syncthreads();
  const int t = threadIdx.x;
  if (t < 128) {
    const int nl = t & 31, lq = t >> 5;
    const int n = n0 + nl;
    const int Kt = K >> 5;
    u16x8 o;
#pragma unroll
    for (int j = 0; j < 4; ++j) o[j] = f2bf(tile[4 * lq + j][nl]);
#pragma unroll
    for (int j = 0; j < 4; ++j) o[4 + j] = f2bf(tile[4 * lq + 16 + j][nl]);
    size_t base = ((size_t)((n >> 4) * Kt + (k0 >> 5)) << 9)
                + (((lq << 4) | (n & 15)) << 3);
    *(u16x8*)(out + base) = o;
  }
}

// ---- pack weight hi/lo: W[K][N] f32 -> two packed bf16 (v = hi + lo) ----
__global__ __launch_bounds__(256)
void pack_w_hl(const float* __restrict__ Wm, u16* __restrict__ oh,
               u16* __restrict__ ol, int K, int N) {
  __shared__ float tile[32][33];
  const int n0 = blockIdx.x * 32, k0 = blockIdx.y * 32;
  const int c = threadIdx.x & 31, r = threadIdx.x >> 5;
#pragma unroll
  for (int rr = 0; rr < 32; rr += 8)
    tile[rr + r][c] = Wm[(size_t)(k0 + rr + r) * N + n0 + c];
  __syncthreads();
  const int t = threadIdx.x;
  if (t < 128) {
    const int nl = t & 31, lq = t >> 5;
    const int n = n0 + nl;
    const int Kt = K >> 5;
    u16x8 vh, vl;
#pragma unroll
    for (int j = 0; j < 8; ++j) {
      float f = tile[4 * lq + (j & 3) + 16 * (j >> 2)][nl];
      u16 h = f2bf(f);
      vh[j] = h;
      vl[j] = f2bf(f - bf2f(h));
    }
    size_t base = ((size_t)((n >> 4) * Kt + (k0 >> 5)) << 9)
                + (((lq << 4) | (n & 15)) << 3);
    *(u16x8*)(oh + base) = vh;
    *(u16x8*)(ol + base) = vl;
  }
}

// ---- bf16 MFMA GEMM, fragment-packed, BK=64, double-buffer counted-vmcnt ----
template <int EPI, int BM, int BN>
__global__ __launch_bounds__(256)
void gemm_bt(const u16* __restrict__ A, const u16* __restrict__ BT,
             int KtA, int KtB, int ktn, int M, int N,
             float* __restrict__ O0, u16* __restrict__ O1, int halfN) {
  constexpr int SEGA = (BM / 16) * 2, SEGB = (BN / 16) * 2;  // 1KB segs / step
  constexpr int LPW = (SEGA + SEGB) / 4;                      // gloads per wave
  constexpr int FI = BM / 32, FJ = BN / 32;
  constexpr int BUFA = BM * 64, BUFB = BN * 64;               // u16 per buffer
  __shared__ u16 As[2 * BUFA];
  __shared__ u16 Bs[2 * BUFB];

  // bijective XCD swizzle on the xy-plane (nwg % 8 == 0 for all launches)
  const int nwg = gridDim.x * gridDim.y;
  int wg = blockIdx.y * gridDim.x + blockIdx.x;
  wg = (wg & 7) * (nwg >> 3) + (wg >> 3);
  const int bx = wg % gridDim.x, by = wg / gridDim.x;
  const int kt0 = blockIdx.z * ktn * 2;
  float* __restrict__ O0z = O0 + (size_t)blockIdx.z * M * N;

  const int t = threadIdx.x;
  const int m0 = by * BM, n0 = bx * BN;
  const int lane = t & 63, wid = t >> 6;
  const int wm = (wid >> 1) * (BM / 2), wn = (wid & 1) * (BN / 2);
  const int lr = lane & 15, lq = lane >> 4;
  const int ga = m0 >> 4, gb = n0 >> 4;

  f32x4 acc[FI][FJ];
#pragma unroll
  for (int i = 0; i < FI; ++i)
#pragma unroll
    for (int j = 0; j < FJ; ++j) acc[i][j] = f32x4{0.f, 0.f, 0.f, 0.f};

  auto stage = [&](int T, int bi) {
#pragma unroll
    for (int q = 0; q < LPW; ++q) {
      const int s = wid * LPW + q;
      if (s < SEGA) {
        const int g = s >> 1, sk = s & 1;
        gload16(A + (((size_t)(ga + g) * KtA + kt0 + 2 * T + sk) << 9) + lane * 8,
                (char*)As + (size_t)bi * (BUFA * 2) + s * 1024);
      } else {
        const int s2 = s - SEGA, g = s2 >> 1, sk = s2 & 1;
        gload16(BT + (((size_t)(gb + g) * KtB + kt0 + 2 * T + sk) << 9) + lane * 8,
                (char*)Bs + (size_t)bi * (BUFB * 2) + s2 * 1024);
      }
    }
  };

  stage(0, 0);
  int cur = 0;
  for (int T = 0; T < ktn; ++T) {
    if (T + 1 < ktn) { stage(T + 1, cur ^ 1); waitvm<LPW>(); }
    else             { waitvm<0>(); }
    __builtin_amdgcn_s_barrier();
    __builtin_amdgcn_sched_barrier(0);

#pragma unroll
    for (int sk = 0; sk < 2; ++sk) {
      u16x8 af[FI], bfr[FJ];
#pragma unroll
      for (int i = 0; i < FI; ++i)
        af[i] = *(const u16x8*)
            &As[cur * BUFA + (((((wm >> 4) + i) << 1) + sk) << 9) + lane * 8];
#pragma unroll
      for (int j = 0; j < FJ; ++j)
        bfr[j] = *(const u16x8*)
            &Bs[cur * BUFB + (((((wn >> 4) + j) << 1) + sk) << 9) + lane * 8];
#pragma unroll
      for (int i = 0; i < FI; ++i)
#pragma unroll
        for (int j = 0; j < FJ; ++j)
          acc[i][j] = MFMA(af[i], bfr[j], acc[i][j]);
    }

    __builtin_amdgcn_sched_barrier(0);
    __builtin_amdgcn_s_barrier();
    cur ^= 1;
  }

#pragma unroll
  for (int i = 0; i < FI; ++i) {
    const int row0 = m0 + wm + i * 16 + lq * 4;
#pragma unroll
    for (int j = 0; j < FJ; ++j) {
      const int col = n0 + wn + j * 16 + lr;
#pragma unroll
      for (int r = 0; r < 4; ++r) {
        float v = acc[i][j][r];
        const int row = row0 + r;
        if (EPI == 0) {
          O0z[(size_t)row * N + col] = v;
        } else {
          if (col < halfN) {
            O0z[(size_t)row * halfN + col] = v;
          } else {
            O1[(size_t)row * halfN + (col - halfN)] =
                f2bf(v / (1.f + __expf(-v)));
          }
        }
      }
    }
  }
}

// ---- split-bf16 (hi/lo) MFMA GEMM: C = A@B^T with ~fp32 accuracy ----
// A,B given as packed hi/lo pairs. 3 MFMAs: Ah*Bh + Ah*Bl + Al*Bh.
// BK=32 per step, double-buffered, counted vmcnt. 4 waves (2x2).
// EPI 0: partial f32 store to O0 + z*MROWS*N   (proj split-K)
// EPI 1: softplus(acc + bias[col]) -> O0[row*N+col]   (dt)
template <int EPI, int BM, int BN>
__global__ __launch_bounds__(256)
void gemm_hl(const u16* __restrict__ Ahp, const u16* __restrict__ Alp,
             const u16* __restrict__ Bhp, const u16* __restrict__ Blp,
             int KtA, int KtB, int ktn, int N,
             const float* __restrict__ bias, float* __restrict__ O0) {
  constexpr int SA = BM / 16, SB = BN / 16;
  constexpr int LPW = (2 * SA + 2 * SB) / 4;
  constexpr int FI = BM / 32, FJ = BN / 32;
  __shared__ u16 AhS[2 * SA * 512];
  __shared__ u16 AlS[2 * SA * 512];
  __shared__ u16 BhS[2 * SB * 512];
  __shared__ u16 BlS[2 * SB * 512];

  const int t = threadIdx.x;
  const int m0 = blockIdx.y * BM, n0 = blockIdx.x * BN;
  const int kt0 = blockIdx.z * ktn;
  float* __restrict__ O0z = O0 + (size_t)blockIdx.z * MROWS * N;
  const int lane = t & 63, wid = t >> 6;
  const int wm = (wid >> 1) * (BM / 2), wn = (wid & 1) * (BN / 2);
  const int lr = lane & 15, lq = lane >> 4;
  const int ga = m0 >> 4, gb = n0 >> 4;

  f32x4 acc[FI][FJ];
#pragma unroll
  for (int i = 0; i < FI; ++i)
#pragma unroll
    for (int j = 0; j < FJ; ++j) acc[i][j] = f32x4{0.f, 0.f, 0.f, 0.f};

  auto stage = [&](int T, int bi) {
#pragma unroll
    for (int q = 0; q < LPW; ++q) {
      const int s = wid * LPW + q;
      if (s < SA)
        gload16(Ahp + (((size_t)(ga + s) * KtA + kt0 + T) << 9) + lane * 8,
                (char*)AhS + bi * (SA * 1024) + s * 1024);
      else if (s < 2 * SA) {
        const int g = s - SA;
        gload16(Alp + (((size_t)(ga + g) * KtA + kt0 + T) << 9) + lane * 8,
                (char*)AlS + bi * (SA * 1024) + g * 1024);
      } else if (s < 2 * SA + SB) {
        const int g = s - 2 * SA;
        gload16(Bhp + (((size_t)(gb + g) * KtB + kt0 + T) << 9) + lane * 8,
                (char*)BhS + bi * (SB * 1024) + g * 1024);
      } else {
        const int g = s - 2 * SA - SB;
        gload16(Blp + (((size_t)(gb + g) * KtB + kt0 + T) << 9) + lane * 8,
                (char*)BlS + bi * (SB * 1024) + g * 1024);
      }
    }
  };

  stage(0, 0);
  int cur = 0;
  for (int T = 0; T < ktn; ++T) {
    if (T + 1 < ktn) { stage(T + 1, cur ^ 1); waitvm<LPW>(); }
    else             { waitvm<0>(); }
    __builtin_amdgcn_s_barrier();
    __builtin_amdgcn_sched_barrier(0);

    u16x8 ah[FI], al[FI], bh[FJ], bl[FJ];
#pragma unroll
    for (int i = 0; i < FI; ++i) {
      const int off = cur * (SA * 512) + (((wm >> 4) + i) << 9) + lane * 8;
      ah[i] = *(const u16x8*)&AhS[off];
      al[i] = *(const u16x8*)&AlS[off];
    }
#pragma unroll
    for (int j = 0; j < FJ; ++j) {
      const int off = cur * (SB * 512) + (((wn >> 4) + j) << 9) + lane * 8;
      bh[j] = *(const u16x8*)&BhS[off];
      bl[j] = *(const u16x8*)&BlS[off];
    }
#pragma unroll
    for (int i = 0; i < FI; ++i)
#pragma unroll
      for (int j = 0; j < FJ; ++j) {
        acc[i][j] = MFMA(ah[i], bh[j], acc[i][j]);
        acc[i][j] = MFMA(ah[i], bl[j], acc[i][j]);
        acc[i][j] = MFMA(al[i], bh[j], acc[i][j]);
      }

    __builtin_amdgcn_sched_barrier(0);
    __builtin_amdgcn_s_barrier();
    cur ^= 1;
  }

#pragma unroll
  for (int i = 0; i < FI; ++i) {
    const int row0 = m0 + wm + i * 16 + lq * 4;
#pragma unroll
    for (int j = 0; j < FJ; ++j) {
      const int col = n0 + wn + j * 16 + lr;
#pragma unroll
      for (int r = 0; r < 4; ++r) {
        float v = acc[i][j][r];
        const int row = row0 + r;
        if (EPI == 0) {
          O0z[(size_t)row * N + col] = v;
        } else {
          v += bias[col];
          v = (v > 20.f) ? v : log1pf(__expf(v));
          O0z[(size_t)row * N + col] = v;
        }
      }
    }
  }
}

// ---- fixed-order split-K reduce: out = p0 + p1 ----
__global__ __launch_bounds__(256)
void add2(const float* __restrict__ p, float* __restrict__ out) {
  const size_t i = (size_t)(blockIdx.x * 256 + threadIdx.x) * 4;
  f32x4 a = *(const f32x4*)(p + i);
  f32x4 b = *(const f32x4*)(p + (size_t)MROWS * DM + i);
  *(f32x4*)(out + i) = a + b;
}

// ---- depthwise causal conv (k=4) + SiLU; also emits packed hi/lo bf16 ----
__global__ __launch_bounds__(256)
void conv_silu(const float* __restrict__ xin, const float* __restrict__ w,
               const float* __restrict__ cb, float* __restrict__ xc,
               u16* __restrict__ xch, u16* __restrict__ xcl) {
  int idx = blockIdx.x * 256 + threadIdx.x;  // (b, t, d4)
  int d4 = idx & 511;
  int tt = (idx >> 9) & 2047;
  int b = idx >> 20;
  const f32x4* w4 = (const f32x4*)w;
  f32x4 wt[4];
#pragma unroll
  for (int j = 0; j < 4; ++j) wt[j] = w4[d4 * 4 + j];  // taps for d = 4*d4+j
  f32x4 acc = *(const f32x4*)(cb + d4 * 4);
#pragma unroll
  for (int k = 0; k < 4; ++k) {
    int ts = tt - 3 + k;
    if (ts >= 0) {
      f32x4 xv = *(const f32x4*)(xin + ((size_t)(b * 2048 + ts) * 512 + d4) * 4);
      acc[0] += xv[0] * wt[0][k];
      acc[1] += xv[1] * wt[1][k];
      acc[2] += xv[2] * wt[2][k];
      acc[3] += xv[3] * wt[3][k];
    }
  }
  f32x4 o;
#pragma unroll
  for (int j = 0; j < 4; ++j) o[j] = acc[j] / (1.f + __expf(-acc[j]));
  const int m = b * 2048 + tt;
  *(f32x4*)(xc + ((size_t)m * 512 + d4) * 4) = o;
  // packed hi/lo write (proj A operand, KtA = DI/32 = 64)
  const int d0 = d4 * 4;
  u16x4 vh, vl;
#pragma unroll
  for (int e = 0; e < 4; ++e) {
    u16 h = f2bf(o[e]);
    vh[e] = h;
    vl[e] = f2bf(o[e] - bf2f(h));
  }
  size_t base = ((size_t)((m >> 4) * 64 + (d0 >> 5)) << 9)
              + (((((d0 & 15) >> 2) << 4) | (m & 15)) << 3)
              + (((d0 >> 4) & 1) << 2);
  *(u16x4*)(xch + base) = vh;
  *(u16x4*)(xcl + base) = vl;
}

// ---- proj split-K reduce; also emits packed hi/lo dt_in (cols 0..63) ----
__global__ __launch_bounds__(256)
void proj_reduce(const float* __restrict__ part, float* __restrict__ proj,
                 u16* __restrict__ dth, u16* __restrict__ dtl) {
  const int tid = blockIdx.x * 256 + threadIdx.x;
  const size_t i = (size_t)tid * 4;
  f32x4 s = *(const f32x4*)(part + i);
#pragma unroll
  for (int ks = 1; ks < KSLC; ++ks)
    s += *(const f32x4*)(part + (size_t)ks * MROWS * NPROJ + i);
  *(f32x4*)(proj + i) = s;
  const int m = (int)(i / NPROJ), k0 = (int)(i % NPROJ);
  if (k0 < RK) {  // dt_in columns -> packed hi/lo (KtA = RK/32 = 2)
    u16x4 vh, vl;
#pragma unroll
    for (int e = 0; e < 4; ++e) {
      u16 h = f2bf(s[e]);
      vh[e] = h;
      vl[e] = f2bf(s[e] - bf2f(h));
    }
    size_t base = ((size_t)((m >> 4) * 2 + (k0 >> 5)) << 9)
                + (((((k0 & 15) >> 2) << 4) | (m & 15)) << 3)
                + (((k0 >> 4) & 1) << 2);
    *(u16x4*)(dth + base) = vh;
    *(u16x4*)(dtl + base) = vl;
  }
}

// ---- scan pass 1: thread owns d, 16 states in regs. P via exp2(a2*sum(dt)). ----
__global__ __launch_bounds__(256)
void scan1(const float* __restrict__ dt, const float* __restrict__ xc,
           const float* __restrict__ proj, const float* __restrict__ A_log,
           float* __restrict__ P, float* __restrict__ S) {
  __shared__ float Bs[CHUNK][16];
  const int c = blockIdx.x, dblk = blockIdx.y, b = blockIdx.z;
  const int d = (dblk << 8) + threadIdx.x;
  const size_t mbase = (size_t)b * SEQ + (size_t)c * CHUNK;
  if (threadIdx.x < CHUNK * 4) {
    int tt = threadIdx.x >> 2, q = (threadIdx.x & 3) * 4;
    *(f32x4*)&Bs[tt][q] = *(const f32x4*)(proj + (mbase + tt) * NPROJ + RK + q);
  }
  __syncthreads();

  float a2[16], h[16];
#pragma unroll
  for (int i = 0; i < 4; ++i) {
    f32x4 v = *(const f32x4*)(A_log + (size_t)d * NS + i * 4);
    a2[4 * i + 0] = -__expf(v[0]) * LOG2E;
    a2[4 * i + 1] = -__expf(v[1]) * LOG2E;
    a2[4 * i + 2] = -__expf(v[2]) * LOG2E;
    a2[4 * i + 3] = -__expf(v[3]) * LOG2E;
  }
#pragma unroll
  for (int n = 0; n < 16; ++n) h[n] = 0.f;

  float sumdt = 0.f;
  const float* dtp = dt + mbase * DI + d;
  const float* xcp = xc + mbase * DI + d;
  for (int tt = 0; tt < CHUNK; ++tt) {
    float dtv = dtp[(size_t)tt * DI];
    float xv  = xcp[(size_t)tt * DI];
    sumdt += dtv;
    float dx = dtv * xv;
    float Bv[16];
    *(f32x4*)&Bv[0]  = *(const f32x4*)&Bs[tt][0];
    *(f32x4*)&Bv[4]  = *(const f32x4*)&Bs[tt][4];
    *(f32x4*)&Bv[8]  = *(const f32x4*)&Bs[tt][8];
    *(f32x4*)&Bv[12] = *(const f32x4*)&Bs[tt][12];
#pragma unroll
    for (int n = 0; n < 16; ++n)
      h[n] = h[n] * exp2f(dtv * a2[n]) + dx * Bv[n];
  }

  const size_t off = ((size_t)(b * NCH + c) * NS) * DI + d;
#pragma unroll
  for (int n = 0; n < 16; ++n) {
    P[off + (size_t)n * DI] = exp2f(a2[n] * sumdt);
    S[off + (size_t)n * DI] = h[n];
  }
}

// ---- scan pass 2: exclusive scan across chunks ----
__global__ __launch_bounds__(256)
void scan2(const float* __restrict__ P, const float* __restrict__ S,
           float* __restrict__ h0) {
  int idx = blockIdx.x * 256 + threadIdx.x;  // [0, BATCH*NS*DI)
  int b = idx >> 15, rem = idx & 32767;
  float h = 0.f;
#pragma unroll 8
  for (int c = 0; c < NCH; ++c) {
    size_t off = ((size_t)(b * NCH + c) << 15) + rem;
    h0[off] = h;
    h = P[off] * h + S[off];
  }
}

// ---- scan pass 3: recompute with h0; in-register n-reduction; gate+bf16;
//      writes yg in fragment-packed layout for gemm0 (K=DI, Kt=64) ----
__global__ __launch_bounds__(256)
void scan3(const float* __restrict__ dt, const float* __restrict__ xc,
           const float* __restrict__ proj, const float* __restrict__ A_log,
           const float* __restrict__ Dskip, const float* __restrict__ h0,
           const u16* __restrict__ sz, u16* __restrict__ yg) {
  __shared__ float Bs[CHUNK][16];
  __shared__ float Cs[CHUNK][16];
  const int c = blockIdx.x, dblk = blockIdx.y, b = blockIdx.z;
  const int d = (dblk << 8) + threadIdx.x;
  const size_t mbase = (size_t)b * SEQ + (size_t)c * CHUNK;
  if (threadIdx.x < CHUNK * 4) {
    int tt = threadIdx.x >> 2, q = (threadIdx.x & 3) * 4;
    *(f32x4*)&Bs[tt][q] = *(const f32x4*)(proj + (mbase + tt) * NPROJ + RK + q);
  } else if (threadIdx.x < CHUNK * 8) {
    int u = threadIdx.x - CHUNK * 4;
    int tt = u >> 2, q = (u & 3) * 4;
    *(f32x4*)&Cs[tt][q] = *(const f32x4*)(proj + (mbase + tt) * NPROJ + RK + NS + q);
  }
  __syncthreads();

  float a2[16], h[16];
#pragma unroll
  for (int i = 0; i < 4; ++i) {
    f32x4 v = *(const f32x4*)(A_log + (size_t)d * NS + i * 4);
    a2[4 * i + 0] = -__expf(v[0]) * LOG2E;
    a2[4 * i + 1] = -__expf(v[1]) * LOG2E;
    a2[4 * i + 2] = -__expf(v[2]) * LOG2E;
    a2[4 * i + 3] = -__expf(v[3]) * LOG2E;
  }
  const size_t hoff = ((size_t)(b * NCH + c) * NS) * DI + d;
#pragma unroll
  for (int n = 0; n < 16; ++n) h[n] = h0[hoff + (size_t)n * DI];

  const float dsk = Dskip[d];
  const float* dtp = dt + mbase * DI + d;
  const float* xcp = xc + mbase * DI + d;
  const u16*   szp = sz + mbase * DI + d;

  // packed write base for this d (k-index of gemm0's A)
  const size_t dbase = ((size_t)(d >> 5) << 9) + (((d & 15) >> 2) << 7)
                     + ((d & 3) | (((d >> 4) & 1) << 2));
  const size_t mb4 = ((size_t)(mbase >> 4) << 15);

  for (int tt = 0; tt < CHUNK; ++tt) {
    float dtv = dtp[(size_t)tt * DI];
    float xv  = xcp[(size_t)tt * DI];
    float szv = bf2f(szp[(size_t)tt * DI]);
    float dx = dtv * xv;
    float Bv[16], Cv[16];
    *(f32x4*)&Bv[0]  = *(const f32x4*)&Bs[tt][0];
    *(f32x4*)&Bv[4]  = *(const f32x4*)&Bs[tt][4];
    *(f32x4*)&Bv[8]  = *(const f32x4*)&Bs[tt][8];
    *(f32x4*)&Bv[12] = *(const f32x4*)&Bs[tt][12];
    *(f32x4*)&Cv[0]  = *(const f32x4*)&Cs[tt][0];
    *(f32x4*)&Cv[4]  = *(const f32x4*)&Cs[tt][4];
    *(f32x4*)&Cv[8]  = *(const f32x4*)&Cs[tt][8];
    *(f32x4*)&Cv[12] = *(const f32x4*)&Cs[tt][12];
    float y0 = 0.f, y1 = 0.f, y2 = 0.f, y3 = 0.f;
#pragma unroll
    for (int n = 0; n < 16; ++n) {
      h[n] = h[n] * exp2f(dtv * a2[n]) + dx * Bv[n];
      float yv = h[n] * Cv[n];
      if ((n & 3) == 0) y0 += yv;
      else if ((n & 3) == 1) y1 += yv;
      else if ((n & 3) == 2) y2 += yv;
      else y3 += yv;
    }
    float y = (y0 + y1) + (y2 + y3);
    size_t addr = mb4 + ((size_t)(tt >> 4) << 15) + ((size_t)(tt & 15) << 3) + dbase;
    yg[addr] = f2bf((y + xv * dsk) * szv);
  }
}

extern "C" void kernel_launch(void* const* d_in, const int* in_sizes, int n_in,
                              void* d_out, int out_size, void* d_ws, size_t ws_size,
                              hipStream_t stream) {
  const float* x      = (const float*)d_in[0];
  const float* W_in   = (const float*)d_in[1];
  const float* conv_w = (const float*)d_in[2];
  const float* conv_b = (const float*)d_in[3];
  const float* W_xp   = (const float*)d_in[4];
  const float* W_dt   = (const float*)d_in[5];
  const float* b_dt   = (const float*)d_in[6];
  const float* A_log  = (const float*)d_in[7];
  const float* Dskip  = (const float*)d_in[8];
  const float* W_out  = (const float*)d_in[9];
  float* out = (float*)d_out;

  char* w = (char*)d_ws;
  u16* xbf    = (u16*)w;   w += (size_t)MROWS * DM * 2;            // 8 MB (packed)
  u16* WinT   = (u16*)w;   w += (size_t)(2 * DI) * DM * 2;         // 8 MB (packed)
  u16* WoutT  = (u16*)w;   w += (size_t)DM * DI * 2;               // 4 MB (packed)
  float* xin  = (float*)w; w += (size_t)MROWS * DI * 4;            // 32 MB (alias: dtb)
  u16* szb    = (u16*)w;   w += (size_t)MROWS * DI * 2;            // 16 MB (bf16)
  float* xc   = (float*)w; w += (size_t)MROWS * DI * 4;            // 32 MB (alias: gemm0 partials)
  float* proj = (float*)w; w += (size_t)MROWS * NPROJ * 4;         // 1.5 MB
  float* Pb   = (float*)w; w += (size_t)BATCH * NCH * NS * DI * 4; // 16.8 MB (alias: yg, ppart)
  float* Sb   = (float*)w; w += (size_t)BATCH * NCH * NS * DI * 4; // 16.8 MB (alias: xch/xcl lo)
  float* h0b  = (float*)w; w += (size_t)BATCH * NCH * NS * DI * 4; // 16.8 MB (alias: xch/xcl hi)
  float* dtb  = xin;            // xin dead after conv_silu
  u16*   yg   = (u16*)Pb;       // P dead after scan2
  float* ppart = Pb;            // proj partials (12.6 MB), dead before scan1
  float* pK   = xc;             // gemm0 split-K partials; xc dead after scan3
  // packed hi/lo xc: 2 x 16.78 MB == Sb+h0b exactly; dead before scan1/scan2
  u16* xch = (u16*)Sb;
  u16* xcl = xch + (size_t)MROWS * DI;
  // small packed buffers recycled into xbf (dead after gemm1): 2.36 MB total
  u16* WxpTh = xbf;                    // 6*64*512   = 196608 u16
  u16* WxpTl = WxpTh + 196608;
  u16* WdtTh = WxpTl + 196608;         // 128*2*512  = 131072 u16
  u16* WdtTl = WdtTh + 131072;
  u16* dtinH = WdtTl + 131072;         // 256*2*512  = 262144 u16
  u16* dtinL = dtinH + 262144;

  pack_x<<<(MROWS * DM / 8) / 256, 256, 0, stream>>>(x, xbf);
  pack_w<<<dim3((2 * DI) / 32, DM / 32), 256, 0, stream>>>(W_in, WinT, DM, 2 * DI);
  pack_w<<<dim3(DM / 32, DI / 32), 256, 0, stream>>>(W_out, WoutT, DI, DM);

  // gemm1: M=4096, N=4096, K=1024 (ktn=16 BK64-steps)
  gemm_bt<1, 128, 128><<<dim3((2 * DI) / 128, MROWS / 128, 1), 256, 0, stream>>>(
      xbf, WinT, DM / 32, DM / 32, DM / 64, MROWS, 2 * DI, xin, szb, DI);

  conv_silu<<<(MROWS * DI / 4) / 256, 256, 0, stream>>>(xin, conv_w, conv_b,
                                                        xc, xch, xcl);

  // hi/lo packs (into xbf region, dead after gemm1)
  pack_w_hl<<<dim3(NPROJ / 32, DI / 32), 256, 0, stream>>>(W_xp, WxpTh, WxpTl, DI, NPROJ);
  pack_w_hl<<<dim3(DI / 32, RK / 32), 256, 0, stream>>>(W_dt, WdtTh, WdtTl, RK, DI);

  // proj: M=4096, N=96, K=2048, split-K=8 (ktn=8 k-tiles each)
  gemm_hl<0, 64, 96><<<dim3(1, MROWS / 64, KSLC), 256, 0, stream>>>(
      xch, xcl, WxpTh, WxpTl, DI / 32, DI / 32, (DI / 32) / KSLC, NPROJ,
      nullptr, ppart);
  proj_reduce<<<(MROWS * NPROJ / 4) / 256, 256, 0, stream>>>(ppart, proj, dtinH, dtinL);

  // dt: M=4096, N=2048, K=64 (ktn=2), softplus epilogue
  gemm_hl<1, 128, 128><<<dim3(DI / 128, MROWS / 128, 1), 256, 0, stream>>>(
      dtinH, dtinL, WdtTh, WdtTl, RK / 32, RK / 32, RK / 32, DI, b_dt, dtb);

  scan1<<<dim3(NCH, DI / 256, BATCH), 256, 0, stream>>>(dtb, xc, proj, A_log, Pb, Sb);
  scan2<<<(BATCH * NS * DI) / 256, 256, 0, stream>>>(Pb, Sb, h0b);
  scan3<<<dim3(NCH, DI / 256, BATCH), 256, 0, stream>>>(dtb, xc, proj, A_log, Dskip, h0b, szb, yg);

  // gemm0: M=4096, N=1024, K=2048; split-K=2 via blockIdx.z (ktn=16 each)
  gemm_bt<0, 128, 128><<<dim3(DM / 128, MROWS / 128, 2), 256, 0, stream>>>(
      yg, WoutT, DI / 32, DI / 32, DI / 128, MROWS, DM, pK, nullptr, 0);
  add2<<<(MROWS * DM / 4) / 256, 256, 0, stream>>>(pK, out);
}